// Round 9
// baseline (261.339 us; speedup 1.0000x reference)
//
#include <hip/hip_runtime.h>
#include <hip/hip_bf16.h>
#include <math.h>

#define B_ 4
#define T_ 4096
#define D_ 2048
#define E_ 8
#define C_ 1024
#define H_ 256
#define SLOTCAP 32

typedef unsigned short u16;
typedef unsigned long long u64;
typedef __attribute__((ext_vector_type(8))) short short8;
typedef __attribute__((ext_vector_type(4))) float f32x4;

__device__ __forceinline__ u16 f2bf_n(float f) {
    union { __hip_bfloat16 b; u16 u; } v;
    v.b = __float2bfloat16(f);
    return v.u;
}
__device__ __forceinline__ float bf2f(u16 u) {
    union { unsigned u; float f; } v; v.u = ((unsigned)u) << 16;
    return v.f;
}

// swizzled u16 index into a [rows][64] tile image: 8-u16 chunk XOR'd by row&7
__device__ __forceinline__ int swz(int row, int chunk) {
    return (row << 6) + ((chunk ^ (row & 7)) << 3);
}

// async global->LDS, 16B per lane; dst wave-uniform base (HW adds lane*16)
__device__ __forceinline__ void gload16(const void* g, void* l) {
    __builtin_amdgcn_global_load_lds(
        (const __attribute__((address_space(1))) void*)g,
        (__attribute__((address_space(3))) void*)l, 16, 0, 0);
}

// ---------------- x: plain f32 -> bf16 (row-major) ----------------
__global__ __launch_bounds__(256) void conv_x_bf16(
    const float* __restrict__ src, u16* __restrict__ dst, int n)
{
    int i = (blockIdx.x * 256 + threadIdx.x) * 4;
    if (i >= n) return;
    f32x4 v = *reinterpret_cast<const f32x4*>(src + i);
    u16 o[4];
    o[0] = f2bf_n(v[0]); o[1] = f2bf_n(v[1]); o[2] = f2bf_n(v[2]); o[3] = f2bf_n(v[3]);
    *reinterpret_cast<u64*>(dst + i) = *reinterpret_cast<const u64*>(o);
}

// ---------------- W1 -> swizzled tile image ----------------
// image[e][kt(32)][row(256)][sc(8)] : 16B chunk = bf16(W1[e][row][kt*64 + (sc^(row&7))*8 ..+7])
__global__ __launch_bounds__(256) void conv_w1_img(
    const float* __restrict__ W1, u16* __restrict__ img)
{
    const int cid = blockIdx.x * 256 + threadIdx.x;      // 0 .. 512K-1
    const int e = cid >> 16;
    const int kt = (cid >> 11) & 31;
    const int row = (cid >> 3) & 255;
    const int sc = cid & 7;
    const float* s = W1 + (((size_t)e * 256 + row) * 2048 + kt * 64
                           + ((sc ^ (row & 7)) << 3));
    f32x4 v0 = *reinterpret_cast<const f32x4*>(s);
    f32x4 v1 = *reinterpret_cast<const f32x4*>(s + 4);
    u16 o[8];
    #pragma unroll
    for (int j = 0; j < 4; ++j) { o[j] = f2bf_n(v0[j]); o[j + 4] = f2bf_n(v1[j]); }
    *reinterpret_cast<short8*>(img + (size_t)cid * 8) =
        *reinterpret_cast<const short8*>(o);
}

// ---------------- W2 -> swizzled tile image ----------------
// image[e][nt(8)][kt(4)][row(256)][sc(8)] : src row = nt*256+row (d), k = kt*64 (h)
__global__ __launch_bounds__(256) void conv_w2_img(
    const float* __restrict__ W2, u16* __restrict__ img)
{
    const int cid = blockIdx.x * 256 + threadIdx.x;      // 0 .. 512K-1
    const int e = cid >> 16;
    const int nt = (cid >> 13) & 7;
    const int kt = (cid >> 11) & 3;
    const int row = (cid >> 3) & 255;
    const int sc = cid & 7;
    const float* s = W2 + (((size_t)e * 2048 + nt * 256 + row) * 256 + kt * 64
                           + ((sc ^ (row & 7)) << 3));
    f32x4 v0 = *reinterpret_cast<const f32x4*>(s);
    f32x4 v1 = *reinterpret_cast<const f32x4*>(s + 4);
    u16 o[8];
    #pragma unroll
    for (int j = 0; j < 4; ++j) { o[j] = f2bf_n(v0[j]); o[j + 4] = f2bf_n(v1[j]); }
    *reinterpret_cast<short8*>(img + (size_t)cid * 8) =
        *reinterpret_cast<const short8*>(o);
}

// ---------------- GEMM1 v7: m97 structure — single-buffer gload, 2 barriers
// tile 128 c-rows x 256 h (full H), K=2048 (NT=32), 512 thr (8 waves 2Mx4N)
// LDS ~49.5 KB -> 3 blocks/CU; cross-block TLP hides the vmcnt drain.
__global__ __launch_bounds__(512) void gemm1_v7(
    const u16* __restrict__ xbf, const u16* __restrict__ W1img,
    const float* __restrict__ b1, const int* __restrict__ idx,
    u16* __restrict__ Himg)
{
    const int mt = blockIdx.x;          // 0..7
    const int be = blockIdx.y;          // 0..31
    const int b = be >> 3, e = be & 7;
    const int m0 = mt * 128;

    __shared__ __align__(16) u16 As[8192];    // 16 KB
    __shared__ __align__(16) u16 Bs[16384];   // 32 KB
    __shared__ int toks[128];
    __shared__ float bs1[256];

    const int tid = threadIdx.x;
    if (tid < 128) toks[tid] = idx[(b * E_ + e) * C_ + m0 + tid];
    if (tid < 256) bs1[tid] = b1[e * H_ + tid];
    __syncthreads();

    const int lane = tid & 63, wid = tid >> 6;
    const int wm = wid >> 2, wn = wid & 3;
    const int l15 = lane & 15, lk = lane >> 4;

    // per-lane DMA sources: slot s0 = tid covers (row = s0>>3, sc = s0&7)
    const int s0 = tid;
    const int arow0 = s0 >> 3, asc = s0 & 7;
    const int arow1 = arow0 + 64;
    const u16* aSrc0 = xbf + ((size_t)b * T_ + toks[arow0]) * D_
                           + ((asc ^ (arow0 & 7)) << 3);
    const u16* aSrc1 = xbf + ((size_t)b * T_ + toks[arow1]) * D_
                           + ((asc ^ (arow1 & 7)) << 3);
    const u16* bSrc = W1img + (size_t)e * 32 * 16384 + (size_t)s0 * 8;
    const int ldsb = wid * 512;   // wave-uniform LDS base (u16 units)

    f32x4 acc[4][4];
    #pragma unroll
    for (int i = 0; i < 4; ++i)
        #pragma unroll
        for (int j = 0; j < 4; ++j)
            acc[i][j] = (f32x4){0.f, 0.f, 0.f, 0.f};

    const int NT = D_ / 64;  // 32
    for (int t = 0; t < NT; ++t) {
        // issue staging for tile t (6x 16B DMA per thread)
        {
            const u16* b_ = bSrc + (size_t)t * 16384;
            gload16(aSrc0 + t * 64, &As[ldsb]);
            gload16(aSrc1 + t * 64, &As[4096 + ldsb]);
            gload16(b_,             &Bs[ldsb]);
            gload16(b_ + 4096,      &Bs[4096 + ldsb]);
            gload16(b_ + 8192,      &Bs[8192 + ldsb]);
            gload16(b_ + 12288,     &Bs[12288 + ldsb]);
        }
        __syncthreads();   // drains vmcnt(0): tile t visible
        #pragma unroll
        for (int kk = 0; kk < 2; ++kk) {
            short8 af[4], bfr[4];
            #pragma unroll
            for (int m = 0; m < 4; ++m) {
                const int row = wm * 64 + m * 16 + l15;
                af[m] = *reinterpret_cast<const short8*>(&As[swz(row, kk * 4 + lk)]);
            }
            #pragma unroll
            for (int n = 0; n < 4; ++n) {
                const int row = wn * 64 + n * 16 + l15;
                bfr[n] = *reinterpret_cast<const short8*>(&Bs[swz(row, kk * 4 + lk)]);
            }
            __builtin_amdgcn_s_setprio(1);
            #pragma unroll
            for (int m = 0; m < 4; ++m)
                #pragma unroll
                for (int n = 0; n < 4; ++n)
                    acc[m][n] = __builtin_amdgcn_mfma_f32_16x16x32_bf16(
                        bfr[n], af[m], acc[m][n], 0, 0, 0);
            __builtin_amdgcn_s_setprio(0);
        }
        __syncthreads();   // all reads done before next overwrite
    }

    // epilogue: bias + exact gelu -> Himg (gemm2 A-image layout)
    const size_t hblk = ((size_t)(be * 8 + mt) * 4 + wn) * 8192;
    #pragma unroll
    for (int m = 0; m < 4; ++m) {
        const int row = wm * 64 + m * 16 + l15;
        #pragma unroll
        for (int n = 0; n < 4; ++n) {
            const int hb = wn * 64 + n * 16 + lk * 4;
            u16 o[4];
            #pragma unroll
            for (int r = 0; r < 4; ++r) {
                float h = acc[m][n][r] + bs1[hb + r];
                float g = 0.5f * h * (1.0f + erff(h * 0.70710678118f));
                o[r] = f2bf_n(g);
            }
            const int lc = (n * 2 + (lk >> 1)) ^ (row & 7);
            u16* p = Himg + hblk + row * 64 + lc * 8 + (lk & 1) * 4;
            *reinterpret_cast<u64*>(p) = *reinterpret_cast<const u64*>(o);
        }
    }
}

// ---------------- GEMM2 v5: m97 structure — single-buffer gload, 2 barriers
// tile 128 c-rows x 256 d-cols, K=256 (NT=4), 512 thr, grid (64,32)
__global__ __launch_bounds__(512) void gemm2_v5(
    const u16* __restrict__ Himg, const u16* __restrict__ W2img,
    const float* __restrict__ b2, const float* __restrict__ gate,
    u16* __restrict__ Ybuf)
{
    const int mt = blockIdx.x >> 3, nt = blockIdx.x & 7;
    const int be = blockIdx.y;
    const int b = be >> 3, e = be & 7;
    const int m0 = mt * 128, n0 = nt * 256;

    __shared__ __align__(16) u16 As[8192];
    __shared__ __align__(16) u16 Bs[16384];
    __shared__ float gs[128];
    __shared__ float bs2[256];

    const int tid = threadIdx.x;
    if (tid < 128) gs[tid] = gate[(b * E_ + e) * C_ + m0 + tid];
    if (tid < 256) bs2[tid] = b2[n0 + tid];
    __syncthreads();

    const int lane = tid & 63, wid = tid >> 6;
    const int wm = wid >> 2, wn = wid & 3;
    const int l15 = lane & 15, lk = lane >> 4;

    const int s0 = tid;
    const u16* aSrc = Himg + ((size_t)(be * 8 + mt) * 4) * 8192 + (size_t)s0 * 8;
    const u16* bSrc = W2img + ((size_t)(e * 8 + nt) * 4) * 16384 + (size_t)s0 * 8;
    const int ldsb = wid * 512;

    f32x4 acc[4][4];
    #pragma unroll
    for (int i = 0; i < 4; ++i)
        #pragma unroll
        for (int j = 0; j < 4; ++j)
            acc[i][j] = (f32x4){0.f, 0.f, 0.f, 0.f};

    const int NT = H_ / 64;  // 4
    for (int t = 0; t < NT; ++t) {
        {
            const u16* a_ = aSrc + (size_t)t * 8192;
            const u16* b_ = bSrc + (size_t)t * 16384;
            gload16(a_,         &As[ldsb]);
            gload16(a_ + 4096,  &As[4096 + ldsb]);
            gload16(b_,         &Bs[ldsb]);
            gload16(b_ + 4096,  &Bs[4096 + ldsb]);
            gload16(b_ + 8192,  &Bs[8192 + ldsb]);
            gload16(b_ + 12288, &Bs[12288 + ldsb]);
        }
        __syncthreads();
        #pragma unroll
        for (int kk = 0; kk < 2; ++kk) {
            short8 af[4], bfr[4];
            #pragma unroll
            for (int m = 0; m < 4; ++m) {
                const int row = wm * 64 + m * 16 + l15;
                af[m] = *reinterpret_cast<const short8*>(&As[swz(row, kk * 4 + lk)]);
            }
            #pragma unroll
            for (int n = 0; n < 4; ++n) {
                const int row = wn * 64 + n * 16 + l15;
                bfr[n] = *reinterpret_cast<const short8*>(&Bs[swz(row, kk * 4 + lk)]);
            }
            __builtin_amdgcn_s_setprio(1);
            #pragma unroll
            for (int m = 0; m < 4; ++m)
                #pragma unroll
                for (int n = 0; n < 4; ++n)
                    acc[m][n] = __builtin_amdgcn_mfma_f32_16x16x32_bf16(
                        bfr[n], af[m], acc[m][n], 0, 0, 0);
            __builtin_amdgcn_s_setprio(0);
        }
        __syncthreads();
    }

    // epilogue: (acc + b2) * gate -> bf16 Ybuf row-major, packed 8B stores
    const size_t ybase = (size_t)(b * E_ + e) * C_ + m0;
    #pragma unroll
    for (int m = 0; m < 4; ++m) {
        const int cl = wm * 64 + m * 16 + l15;
        const float g = gs[cl];
        u16* rowp = Ybuf + (ybase + cl) * (size_t)D_ + n0;
        #pragma unroll
        for (int n = 0; n < 4; ++n) {
            const int db = wn * 64 + n * 16 + lk * 4;
            u16 o[4];
            #pragma unroll
            for (int r = 0; r < 4; ++r)
                o[r] = f2bf_n((acc[m][n][r] + bs2[db + r]) * g);
            *reinterpret_cast<u64*>(rowp + db) = *reinterpret_cast<const u64*>(o);
        }
    }
}

// ---------------- inverted index build ----------------
__global__ __launch_bounds__(256) void fill_kernel(
    const int* __restrict__ idx, int* __restrict__ cnt,
    int* __restrict__ slots)
{
    int i = blockIdx.x * 256 + threadIdx.x;
    if (i >= B_ * E_ * C_) return;
    int b = i / (E_ * C_);
    int slot = i % (E_ * C_);
    int t = idx[i];
    int p = atomicAdd(&cnt[b * T_ + t], 1);
    if (p < SLOTCAP) slots[(b * T_ + t) * SLOTCAP + p] = slot;
}

// ---------------- combine: out[b,t,:] = sum over slots of Ybuf ----------------
__global__ __launch_bounds__(256) void combine_kernel(
    const u16* __restrict__ Ybuf, const int* __restrict__ cnt,
    const int* __restrict__ slots, float* __restrict__ out)
{
    const int bt = blockIdx.x;               // b*T_ + t
    const int tid = threadIdx.x;
    __shared__ int sl[SLOTCAP];
    int n = cnt[bt];
    n = n > SLOTCAP ? SLOTCAP : n;
    if (tid < n) sl[tid] = slots[bt * SLOTCAP + tid];
    __syncthreads();
    const int b = bt >> 12;                  // T_ = 4096
    float a[8] = {0.f, 0.f, 0.f, 0.f, 0.f, 0.f, 0.f, 0.f};
    for (int s = 0; s < n; ++s) {
        const u16* yrow = Ybuf + ((size_t)b * (E_ * C_) + sl[s]) * D_ + tid * 8;
        short8 v = *reinterpret_cast<const short8*>(yrow);
        #pragma unroll
        for (int j = 0; j < 8; ++j) a[j] += bf2f((u16)v[j]);
    }
    float* orow = out + (size_t)bt * D_ + tid * 8;
    *reinterpret_cast<f32x4*>(orow)     = (f32x4){a[0], a[1], a[2], a[3]};
    *reinterpret_cast<f32x4*>(orow + 4) = (f32x4){a[4], a[5], a[6], a[7]};
}

extern "C" void kernel_launch(void* const* d_in, const int* in_sizes, int n_in,
                              void* d_out, int out_size, void* d_ws, size_t ws_size,
                              hipStream_t stream) {
    const float* x    = (const float*)d_in[0];
    const float* W1   = (const float*)d_in[1];
    const float* b1   = (const float*)d_in[2];
    const float* W2   = (const float*)d_in[3];
    const float* b2   = (const float*)d_in[4];
    const int*   idx  = (const int*)d_in[5];
    const float* gate = (const float*)d_in[6];
    float* out = (float*)d_out;

    const size_t nW = (size_t)E_ * H_ * D_;        // 4,194,304
    const size_t nX = (size_t)B_ * T_ * D_;        // 33,554,432
    const size_t nH = (size_t)B_ * E_ * C_ * H_;   // 8,388,608
    const size_t nY = (size_t)B_ * E_ * C_ * D_;   // 67,108,864

    // ws layout: [W1img][W2img][Himg][Ybuf (aliased as xbf)][cnt][slots]
    u16* W1img = (u16*)d_ws;
    u16* W2img = W1img + nW;
    u16* Himg  = W2img + nW;
    u16* Ybuf  = Himg + nH;
    u16* xbf   = Ybuf;                 // alias: xbf dead before gemm2 writes Ybuf
    int* cnt   = (int*)(Ybuf + nY);
    int* slots = cnt + (size_t)B_ * T_;

    hipMemsetAsync(cnt, 0, (size_t)B_ * T_ * sizeof(int), stream);
    conv_w1_img<<<2048, 256, 0, stream>>>(W1, W1img);
    conv_w2_img<<<2048, 256, 0, stream>>>(W2, W2img);
    conv_x_bf16<<<(int)(nX / 1024), 256, 0, stream>>>(x, xbf, (int)nX);
    fill_kernel<<<(B_ * E_ * C_) / 256, 256, 0, stream>>>(idx, cnt, slots);

    gemm1_v7<<<dim3(8, 32), 512, 0, stream>>>(xbf, W1img, b1, idx, Himg);
    gemm2_v5<<<dim3(64, 32), 512, 0, stream>>>(Himg, W2img, b2, gate, Ybuf);
    combine_kernel<<<B_ * T_, 256, 0, stream>>>(Ybuf, cnt, slots, out);
}

// Round 10
// 223.858 us; speedup vs baseline: 1.1674x; 1.1674x over previous
//
#include <hip/hip_runtime.h>
#include <hip/hip_bf16.h>
#include <math.h>

#define B_ 4
#define T_ 4096
#define D_ 2048
#define E_ 8
#define C_ 1024
#define H_ 256
#define SLOTCAP 32

typedef unsigned short u16;
typedef unsigned long long u64;
typedef __attribute__((ext_vector_type(8))) short short8;
typedef __attribute__((ext_vector_type(4))) float f32x4;

__device__ __forceinline__ u16 f2bf_n(float f) {
    union { __hip_bfloat16 b; u16 u; } v;
    v.b = __float2bfloat16(f);
    return v.u;
}
__device__ __forceinline__ float bf2f(u16 u) {
    union { unsigned u; float f; } v; v.u = ((unsigned)u) << 16;
    return v.f;
}

// swizzled u16 index into a [rows][64] tile image: 8-u16 chunk XOR'd by row&7
__device__ __forceinline__ int swz(int row, int chunk) {
    return (row << 6) + ((chunk ^ (row & 7)) << 3);
}

// async global->LDS, 16B per lane; dst wave-uniform base (HW adds lane*16)
__device__ __forceinline__ void gload16(const void* g, void* l) {
    __builtin_amdgcn_global_load_lds(
        (const __attribute__((address_space(1))) void*)g,
        (__attribute__((address_space(3))) void*)l, 16, 0, 0);
}

// ---------------- x: plain f32 -> bf16 (row-major) ----------------
__global__ __launch_bounds__(256) void conv_x_bf16(
    const float* __restrict__ src, u16* __restrict__ dst, int n)
{
    int i = (blockIdx.x * 256 + threadIdx.x) * 4;
    if (i >= n) return;
    f32x4 v = *reinterpret_cast<const f32x4*>(src + i);
    u16 o[4];
    o[0] = f2bf_n(v[0]); o[1] = f2bf_n(v[1]); o[2] = f2bf_n(v[2]); o[3] = f2bf_n(v[3]);
    *reinterpret_cast<u64*>(dst + i) = *reinterpret_cast<const u64*>(o);
}

// ---------------- W1 -> swizzled tile image ----------------
// image[e][kt(32)][row(256)][sc(8)] : chunk = bf16(W1[e][row][kt*64 + (sc^(row&7))*8..])
__global__ __launch_bounds__(256) void conv_w1_img(
    const float* __restrict__ W1, u16* __restrict__ img)
{
    const int cid = blockIdx.x * 256 + threadIdx.x;
    const int e = cid >> 16;
    const int kt = (cid >> 11) & 31;
    const int row = (cid >> 3) & 255;
    const int sc = cid & 7;
    const float* s = W1 + (((size_t)e * 256 + row) * 2048 + kt * 64
                           + ((sc ^ (row & 7)) << 3));
    f32x4 v0 = *reinterpret_cast<const f32x4*>(s);
    f32x4 v1 = *reinterpret_cast<const f32x4*>(s + 4);
    u16 o[8];
    #pragma unroll
    for (int j = 0; j < 4; ++j) { o[j] = f2bf_n(v0[j]); o[j + 4] = f2bf_n(v1[j]); }
    *reinterpret_cast<short8*>(img + (size_t)cid * 8) =
        *reinterpret_cast<const short8*>(o);
}

// ---------------- W2 -> swizzled tile image ----------------
// image[e][nt(8)][kt(4)][row(256)][sc(8)]
__global__ __launch_bounds__(256) void conv_w2_img(
    const float* __restrict__ W2, u16* __restrict__ img)
{
    const int cid = blockIdx.x * 256 + threadIdx.x;
    const int e = cid >> 16;
    const int nt = (cid >> 13) & 7;
    const int kt = (cid >> 11) & 3;
    const int row = (cid >> 3) & 255;
    const int sc = cid & 7;
    const float* s = W2 + (((size_t)e * 2048 + nt * 256 + row) * 256 + kt * 64
                           + ((sc ^ (row & 7)) << 3));
    f32x4 v0 = *reinterpret_cast<const f32x4*>(s);
    f32x4 v1 = *reinterpret_cast<const f32x4*>(s + 4);
    u16 o[8];
    #pragma unroll
    for (int j = 0; j < 4; ++j) { o[j] = f2bf_n(v0[j]); o[j + 4] = f2bf_n(v1[j]); }
    *reinterpret_cast<short8*>(img + (size_t)cid * 8) =
        *reinterpret_cast<const short8*>(o);
}

// ---------------- GEMM1 v8: 64x256 tile, depth-2 gload dbuf, 2 blocks/CU ---
// grid (x=32 be -> XCD=e, y=16 mt), 512 thr (8 waves 2Mx4N, wave 32x64)
// LDS exactly 80KB: As 2x8KB + Bs 2x32KB. Himg out = 64-row tile images.
__global__ __launch_bounds__(512) void gemm1_v8(
    const u16* __restrict__ xbf, const u16* __restrict__ W1img,
    const float* __restrict__ b1, const int* __restrict__ idx,
    u16* __restrict__ Himg)
{
    const int be = blockIdx.x;          // XCD = be%8 = e
    const int mt = blockIdx.y;          // 0..15
    const int b = be >> 3, e = be & 7;
    const int m0 = mt * 64;

    __shared__ __align__(16) u16 As[2][4096];    // 8 KB each
    __shared__ __align__(16) u16 Bs[2][16384];   // 32 KB each

    const int tid = threadIdx.x;
    const int lane = tid & 63, wid = tid >> 6;
    const int wm = wid >> 2, wn = wid & 3;
    const int l15 = lane & 15, lk = lane >> 4;

    // per-lane DMA source: slot tid covers (row = tid>>3, sc = tid&7)
    const int row8 = tid >> 3, asc = tid & 7;
    const int tok = idx[(b * E_ + e) * C_ + m0 + row8];
    const u16* aSrc = xbf + ((size_t)b * T_ + tok) * D_
                          + ((asc ^ (row8 & 7)) << 3);
    const u16* bSrc = W1img + (size_t)e * 32 * 16384 + (size_t)tid * 8;
    const int wofs = wid * 512;   // wave-uniform LDS base (u16)

#define G1_ISSUE(buf, t)                                                      \
    do {                                                                      \
        gload16(aSrc + (t) * 64, &As[buf][wofs]);                             \
        const u16* b_ = bSrc + (size_t)(t) * 16384;                           \
        gload16(b_,         &Bs[buf][wofs]);                                  \
        gload16(b_ + 4096,  &Bs[buf][4096 + wofs]);                           \
        gload16(b_ + 8192,  &Bs[buf][8192 + wofs]);                           \
        gload16(b_ + 12288, &Bs[buf][12288 + wofs]);                          \
    } while (0)

    f32x4 acc[2][4];
    #pragma unroll
    for (int i = 0; i < 2; ++i)
        #pragma unroll
        for (int j = 0; j < 4; ++j)
            acc[i][j] = (f32x4){0.f, 0.f, 0.f, 0.f};

    G1_ISSUE(0, 0);
    G1_ISSUE(1, 1);

    const int NT = D_ / 64;  // 32
    for (int t = 0; t < NT; ++t) {
        const int cur = t & 1;
        if (t < NT - 1) asm volatile("s_waitcnt vmcnt(5)" ::: "memory");
        else            asm volatile("s_waitcnt vmcnt(0)" ::: "memory");
        __builtin_amdgcn_s_barrier();
        __builtin_amdgcn_sched_barrier(0);
        #pragma unroll
        for (int kk = 0; kk < 2; ++kk) {
            short8 af[2], bfr[4];
            #pragma unroll
            for (int m = 0; m < 2; ++m) {
                const int row = wm * 32 + m * 16 + l15;
                af[m] = *reinterpret_cast<const short8*>(
                    &As[cur][swz(row, kk * 4 + lk)]);
            }
            #pragma unroll
            for (int n = 0; n < 4; ++n) {
                const int row = wn * 64 + n * 16 + l15;
                bfr[n] = *reinterpret_cast<const short8*>(
                    &Bs[cur][swz(row, kk * 4 + lk)]);
            }
            __builtin_amdgcn_s_setprio(1);
            #pragma unroll
            for (int m = 0; m < 2; ++m)
                #pragma unroll
                for (int n = 0; n < 4; ++n)
                    acc[m][n] = __builtin_amdgcn_mfma_f32_16x16x32_bf16(
                        bfr[n], af[m], acc[m][n], 0, 0, 0);
            __builtin_amdgcn_s_setprio(0);
        }
        asm volatile("s_waitcnt lgkmcnt(0)" ::: "memory");
        __builtin_amdgcn_s_barrier();
        __builtin_amdgcn_sched_barrier(0);
        if (t + 2 < NT) G1_ISSUE(cur, t + 2);
    }
#undef G1_ISSUE

    // epilogue: bias + exact gelu -> Himg (gemm2 64-row A-image layout)
    // Himg[((be*16+mt)*4 + kt)*4096 + row*64 + (lc^(row&7))*8 + e_off], kt = wn
    const size_t hblk = ((size_t)(be * 16 + mt) * 4 + wn) * 4096;
    #pragma unroll
    for (int m = 0; m < 2; ++m) {
        const int row = wm * 32 + m * 16 + l15;
        #pragma unroll
        for (int n = 0; n < 4; ++n) {
            const int hb = wn * 64 + n * 16 + lk * 4;
            f32x4 bias = *reinterpret_cast<const f32x4*>(&b1[e * H_ + hb]);
            u16 o[4];
            #pragma unroll
            for (int r = 0; r < 4; ++r) {
                float h = acc[m][n][r] + bias[r];
                float g = 0.5f * h * (1.0f + erff(h * 0.70710678118f));
                o[r] = f2bf_n(g);
            }
            const int lc = (n * 2 + (lk >> 1)) ^ (row & 7);
            u16* p = Himg + hblk + row * 64 + lc * 8 + (lk & 1) * 4;
            *reinterpret_cast<u64*>(p) = *reinterpret_cast<const u64*>(o);
        }
    }
}

// ---------------- GEMM2 v6: 64x256 tile, depth-2 gload dbuf, 2 blocks/CU ---
// grid (x=32 be -> XCD=e, y=128 = mt*8+nt), 512 thr, K=256 (NT=4)
__global__ __launch_bounds__(512) void gemm2_v6(
    const u16* __restrict__ Himg, const u16* __restrict__ W2img,
    const float* __restrict__ b2, const float* __restrict__ gate,
    u16* __restrict__ Ybuf)
{
    const int be = blockIdx.x;
    const int yy = blockIdx.y;
    const int mt = yy >> 3, nt = yy & 7;
    const int b = be >> 3, e = be & 7;
    const int m0 = mt * 64, n0 = nt * 256;

    __shared__ __align__(16) u16 As[2][4096];
    __shared__ __align__(16) u16 Bs[2][16384];

    const int tid = threadIdx.x;
    const int lane = tid & 63, wid = tid >> 6;
    const int wm = wid >> 2, wn = wid & 3;
    const int l15 = lane & 15, lk = lane >> 4;

    const u16* aSrc = Himg + ((size_t)(be * 16 + mt) * 4) * 4096 + (size_t)tid * 8;
    const u16* bSrc = W2img + ((size_t)(e * 8 + nt) * 4) * 16384 + (size_t)tid * 8;
    const int wofs = wid * 512;

#define G2_ISSUE(buf, t)                                                      \
    do {                                                                      \
        gload16(aSrc + (size_t)(t) * 4096, &As[buf][wofs]);                   \
        const u16* b_ = bSrc + (size_t)(t) * 16384;                           \
        gload16(b_,         &Bs[buf][wofs]);                                  \
        gload16(b_ + 4096,  &Bs[buf][4096 + wofs]);                           \
        gload16(b_ + 8192,  &Bs[buf][8192 + wofs]);                           \
        gload16(b_ + 12288, &Bs[buf][12288 + wofs]);                          \
    } while (0)

    f32x4 acc[2][4];
    #pragma unroll
    for (int i = 0; i < 2; ++i)
        #pragma unroll
        for (int j = 0; j < 4; ++j)
            acc[i][j] = (f32x4){0.f, 0.f, 0.f, 0.f};

    G2_ISSUE(0, 0);
    G2_ISSUE(1, 1);

    const int NT = H_ / 64;  // 4
    for (int t = 0; t < NT; ++t) {
        const int cur = t & 1;
        if (t < NT - 1) asm volatile("s_waitcnt vmcnt(5)" ::: "memory");
        else            asm volatile("s_waitcnt vmcnt(0)" ::: "memory");
        __builtin_amdgcn_s_barrier();
        __builtin_amdgcn_sched_barrier(0);
        #pragma unroll
        for (int kk = 0; kk < 2; ++kk) {
            short8 af[2], bfr[4];
            #pragma unroll
            for (int m = 0; m < 2; ++m) {
                const int row = wm * 32 + m * 16 + l15;
                af[m] = *reinterpret_cast<const short8*>(
                    &As[cur][swz(row, kk * 4 + lk)]);
            }
            #pragma unroll
            for (int n = 0; n < 4; ++n) {
                const int row = wn * 64 + n * 16 + l15;
                bfr[n] = *reinterpret_cast<const short8*>(
                    &Bs[cur][swz(row, kk * 4 + lk)]);
            }
            __builtin_amdgcn_s_setprio(1);
            #pragma unroll
            for (int m = 0; m < 2; ++m)
                #pragma unroll
                for (int n = 0; n < 4; ++n)
                    acc[m][n] = __builtin_amdgcn_mfma_f32_16x16x32_bf16(
                        bfr[n], af[m], acc[m][n], 0, 0, 0);
            __builtin_amdgcn_s_setprio(0);
        }
        asm volatile("s_waitcnt lgkmcnt(0)" ::: "memory");
        __builtin_amdgcn_s_barrier();
        __builtin_amdgcn_sched_barrier(0);
        if (t + 2 < NT) G2_ISSUE(cur, t + 2);
    }
#undef G2_ISSUE

    // epilogue: (acc + b2) * gate -> bf16 Ybuf row-major
    const size_t ybase = (size_t)(b * E_ + e) * C_ + m0;
    #pragma unroll
    for (int m = 0; m < 2; ++m) {
        const int cl = wm * 32 + m * 16 + l15;
        const float g = gate[ybase + cl];
        u16* rowp = Ybuf + (ybase + cl) * (size_t)D_ + n0;
        #pragma unroll
        for (int n = 0; n < 4; ++n) {
            const int db = wn * 64 + n * 16 + lk * 4;
            f32x4 bias = *reinterpret_cast<const f32x4*>(&b2[n0 + db]);
            u16 o[4];
            #pragma unroll
            for (int r = 0; r < 4; ++r)
                o[r] = f2bf_n((acc[m][n][r] + bias[r]) * g);
            *reinterpret_cast<u64*>(rowp + db) = *reinterpret_cast<const u64*>(o);
        }
    }
}

// ---------------- inverted index build ----------------
__global__ __launch_bounds__(256) void fill_kernel(
    const int* __restrict__ idx, int* __restrict__ cnt,
    int* __restrict__ slots)
{
    int i = blockIdx.x * 256 + threadIdx.x;
    if (i >= B_ * E_ * C_) return;
    int b = i / (E_ * C_);
    int slot = i % (E_ * C_);
    int t = idx[i];
    int p = atomicAdd(&cnt[b * T_ + t], 1);
    if (p < SLOTCAP) slots[(b * T_ + t) * SLOTCAP + p] = slot;
}

// ---------------- combine: out[b,t,:] = sum over slots of Ybuf ----------------
__global__ __launch_bounds__(256) void combine_kernel(
    const u16* __restrict__ Ybuf, const int* __restrict__ cnt,
    const int* __restrict__ slots, float* __restrict__ out)
{
    const int bt = blockIdx.x;               // b*T_ + t
    const int tid = threadIdx.x;
    __shared__ int sl[SLOTCAP];
    int n = cnt[bt];
    n = n > SLOTCAP ? SLOTCAP : n;
    if (tid < n) sl[tid] = slots[bt * SLOTCAP + tid];
    __syncthreads();
    const int b = bt >> 12;                  // T_ = 4096
    float a[8] = {0.f, 0.f, 0.f, 0.f, 0.f, 0.f, 0.f, 0.f};
    for (int s = 0; s < n; ++s) {
        const u16* yrow = Ybuf + ((size_t)b * (E_ * C_) + sl[s]) * D_ + tid * 8;
        short8 v = *reinterpret_cast<const short8*>(yrow);
        #pragma unroll
        for (int j = 0; j < 8; ++j) a[j] += bf2f((u16)v[j]);
    }
    float* orow = out + (size_t)bt * D_ + tid * 8;
    *reinterpret_cast<f32x4*>(orow)     = (f32x4){a[0], a[1], a[2], a[3]};
    *reinterpret_cast<f32x4*>(orow + 4) = (f32x4){a[4], a[5], a[6], a[7]};
}

extern "C" void kernel_launch(void* const* d_in, const int* in_sizes, int n_in,
                              void* d_out, int out_size, void* d_ws, size_t ws_size,
                              hipStream_t stream) {
    const float* x    = (const float*)d_in[0];
    const float* W1   = (const float*)d_in[1];
    const float* b1   = (const float*)d_in[2];
    const float* W2   = (const float*)d_in[3];
    const float* b2   = (const float*)d_in[4];
    const int*   idx  = (const int*)d_in[5];
    const float* gate = (const float*)d_in[6];
    float* out = (float*)d_out;

    const size_t nW = (size_t)E_ * H_ * D_;        // 4,194,304
    const size_t nX = (size_t)B_ * T_ * D_;        // 33,554,432
    const size_t nH = (size_t)B_ * E_ * C_ * H_;   // 8,388,608
    const size_t nY = (size_t)B_ * E_ * C_ * D_;   // 67,108,864

    // ws layout: [W1img][W2img][Himg][Ybuf (aliased as xbf)][cnt][slots]
    u16* W1img = (u16*)d_ws;
    u16* W2img = W1img + nW;
    u16* Himg  = W2img + nW;
    u16* Ybuf  = Himg + nH;
    u16* xbf   = Ybuf;                 // alias: xbf dead before gemm2 writes Ybuf
    int* cnt   = (int*)(Ybuf + nY);
    int* slots = cnt + (size_t)B_ * T_;

    hipMemsetAsync(cnt, 0, (size_t)B_ * T_ * sizeof(int), stream);
    conv_w1_img<<<2048, 256, 0, stream>>>(W1, W1img);
    conv_w2_img<<<2048, 256, 0, stream>>>(W2, W2img);
    conv_x_bf16<<<(int)(nX / 1024), 256, 0, stream>>>(x, xbf, (int)nX);
    fill_kernel<<<(B_ * E_ * C_) / 256, 256, 0, stream>>>(idx, cnt, slots);

    gemm1_v8<<<dim3(32, 16), 512, 0, stream>>>(xbf, W1img, b1, idx, Himg);
    gemm2_v6<<<dim3(32, 128), 512, 0, stream>>>(Himg, W2img, b2, gate, Ybuf);
    combine_kernel<<<B_ * T_, 256, 0, stream>>>(Ybuf, cnt, slots, out);
}

// Round 11
// 218.279 us; speedup vs baseline: 1.1973x; 1.0256x over previous
//
#include <hip/hip_runtime.h>
#include <hip/hip_bf16.h>
#include <math.h>

#define B_ 4
#define T_ 4096
#define D_ 2048
#define E_ 8
#define C_ 1024
#define H_ 256
#define SLOTCAP 32

typedef unsigned short u16;
typedef unsigned long long u64;
typedef __attribute__((ext_vector_type(8))) short short8;
typedef __attribute__((ext_vector_type(4))) float f32x4;

__device__ __forceinline__ u16 f2bf_n(float f) {
    union { __hip_bfloat16 b; u16 u; } v;
    v.b = __float2bfloat16(f);
    return v.u;
}
__device__ __forceinline__ float bf2f(u16 u) {
    union { unsigned u; float f; } v; v.u = ((unsigned)u) << 16;
    return v.f;
}

// swizzled u16 index into a [rows][64] tile image: 8-u16 chunk XOR'd by row&7
__device__ __forceinline__ int swz(int row, int chunk) {
    return (row << 6) + ((chunk ^ (row & 7)) << 3);
}

// async global->LDS, 16B per lane; dst wave-uniform base (HW adds lane*16)
__device__ __forceinline__ void gload16(const void* g, void* l) {
    __builtin_amdgcn_global_load_lds(
        (const __attribute__((address_space(1))) void*)g,
        (__attribute__((address_space(3))) void*)l, 16, 0, 0);
}

// ---------------- x: plain f32 -> bf16 (row-major) ----------------
__global__ __launch_bounds__(256) void conv_x_bf16(
    const float* __restrict__ src, u16* __restrict__ dst, int n)
{
    int i = (blockIdx.x * 256 + threadIdx.x) * 4;
    if (i >= n) return;
    f32x4 v = *reinterpret_cast<const f32x4*>(src + i);
    u16 o[4];
    o[0] = f2bf_n(v[0]); o[1] = f2bf_n(v[1]); o[2] = f2bf_n(v[2]); o[3] = f2bf_n(v[3]);
    *reinterpret_cast<u64*>(dst + i) = *reinterpret_cast<const u64*>(o);
}

// ---------------- W1 -> swizzled tile image ----------------
__global__ __launch_bounds__(256) void conv_w1_img(
    const float* __restrict__ W1, u16* __restrict__ img)
{
    const int cid = blockIdx.x * 256 + threadIdx.x;
    const int e = cid >> 16;
    const int kt = (cid >> 11) & 31;
    const int row = (cid >> 3) & 255;
    const int sc = cid & 7;
    const float* s = W1 + (((size_t)e * 256 + row) * 2048 + kt * 64
                           + ((sc ^ (row & 7)) << 3));
    f32x4 v0 = *reinterpret_cast<const f32x4*>(s);
    f32x4 v1 = *reinterpret_cast<const f32x4*>(s + 4);
    u16 o[8];
    #pragma unroll
    for (int j = 0; j < 4; ++j) { o[j] = f2bf_n(v0[j]); o[j + 4] = f2bf_n(v1[j]); }
    *reinterpret_cast<short8*>(img + (size_t)cid * 8) =
        *reinterpret_cast<const short8*>(o);
}

// ---------------- W2 -> swizzled tile image ----------------
// image[e][nt(8)][kt(4)][row(256)][sc(8)]
__global__ __launch_bounds__(256) void conv_w2_img(
    const float* __restrict__ W2, u16* __restrict__ img)
{
    const int cid = blockIdx.x * 256 + threadIdx.x;
    const int e = cid >> 16;
    const int nt = (cid >> 13) & 7;
    const int kt = (cid >> 11) & 3;
    const int row = (cid >> 3) & 255;
    const int sc = cid & 7;
    const float* s = W2 + (((size_t)e * 2048 + nt * 256 + row) * 256 + kt * 64
                           + ((sc ^ (row & 7)) << 3));
    f32x4 v0 = *reinterpret_cast<const f32x4*>(s);
    f32x4 v1 = *reinterpret_cast<const f32x4*>(s + 4);
    u16 o[8];
    #pragma unroll
    for (int j = 0; j < 4; ++j) { o[j] = f2bf_n(v0[j]); o[j + 4] = f2bf_n(v1[j]); }
    *reinterpret_cast<short8*>(img + (size_t)cid * 8) =
        *reinterpret_cast<const short8*>(o);
}

// ---------------- GEMM1 v8: 64x256 tile, depth-2 gload dbuf, 2 blocks/CU ---
__global__ __launch_bounds__(512) void gemm1_v8(
    const u16* __restrict__ xbf, const u16* __restrict__ W1img,
    const float* __restrict__ b1, const int* __restrict__ idx,
    u16* __restrict__ Himg)
{
    const int be = blockIdx.x;          // XCD = be%8 = e
    const int mt = blockIdx.y;          // 0..15
    const int b = be >> 3, e = be & 7;
    const int m0 = mt * 64;

    __shared__ __align__(16) u16 As[2][4096];
    __shared__ __align__(16) u16 Bs[2][16384];

    const int tid = threadIdx.x;
    const int lane = tid & 63, wid = tid >> 6;
    const int wm = wid >> 2, wn = wid & 3;
    const int l15 = lane & 15, lk = lane >> 4;

    const int row8 = tid >> 3, asc = tid & 7;
    const int tok = idx[(b * E_ + e) * C_ + m0 + row8];
    const u16* aSrc = xbf + ((size_t)b * T_ + tok) * D_
                          + ((asc ^ (row8 & 7)) << 3);
    const u16* bSrc = W1img + (size_t)e * 32 * 16384 + (size_t)tid * 8;
    const int wofs = wid * 512;

#define G1_ISSUE(buf, t)                                                      \
    do {                                                                      \
        gload16(aSrc + (t) * 64, &As[buf][wofs]);                             \
        const u16* b_ = bSrc + (size_t)(t) * 16384;                           \
        gload16(b_,         &Bs[buf][wofs]);                                  \
        gload16(b_ + 4096,  &Bs[buf][4096 + wofs]);                           \
        gload16(b_ + 8192,  &Bs[buf][8192 + wofs]);                           \
        gload16(b_ + 12288, &Bs[buf][12288 + wofs]);                          \
    } while (0)

    f32x4 acc[2][4];
    #pragma unroll
    for (int i = 0; i < 2; ++i)
        #pragma unroll
        for (int j = 0; j < 4; ++j)
            acc[i][j] = (f32x4){0.f, 0.f, 0.f, 0.f};

    G1_ISSUE(0, 0);
    G1_ISSUE(1, 1);

    const int NT = D_ / 64;  // 32
    for (int t = 0; t < NT; ++t) {
        const int cur = t & 1;
        if (t < NT - 1) asm volatile("s_waitcnt vmcnt(5)" ::: "memory");
        else            asm volatile("s_waitcnt vmcnt(0)" ::: "memory");
        __builtin_amdgcn_s_barrier();
        __builtin_amdgcn_sched_barrier(0);
        #pragma unroll
        for (int kk = 0; kk < 2; ++kk) {
            short8 af[2], bfr[4];
            #pragma unroll
            for (int m = 0; m < 2; ++m) {
                const int row = wm * 32 + m * 16 + l15;
                af[m] = *reinterpret_cast<const short8*>(
                    &As[cur][swz(row, kk * 4 + lk)]);
            }
            #pragma unroll
            for (int n = 0; n < 4; ++n) {
                const int row = wn * 64 + n * 16 + l15;
                bfr[n] = *reinterpret_cast<const short8*>(
                    &Bs[cur][swz(row, kk * 4 + lk)]);
            }
            __builtin_amdgcn_s_setprio(1);
            #pragma unroll
            for (int m = 0; m < 2; ++m)
                #pragma unroll
                for (int n = 0; n < 4; ++n)
                    acc[m][n] = __builtin_amdgcn_mfma_f32_16x16x32_bf16(
                        bfr[n], af[m], acc[m][n], 0, 0, 0);
            __builtin_amdgcn_s_setprio(0);
        }
        asm volatile("s_waitcnt lgkmcnt(0)" ::: "memory");
        __builtin_amdgcn_s_barrier();
        __builtin_amdgcn_sched_barrier(0);
        if (t + 2 < NT) G1_ISSUE(cur, t + 2);
    }
#undef G1_ISSUE

    // epilogue: bias + exact gelu -> Himg (64-row tile images)
    const size_t hblk = ((size_t)(be * 16 + mt) * 4 + wn) * 4096;
    #pragma unroll
    for (int m = 0; m < 2; ++m) {
        const int row = wm * 32 + m * 16 + l15;
        #pragma unroll
        for (int n = 0; n < 4; ++n) {
            const int hb = wn * 64 + n * 16 + lk * 4;
            f32x4 bias = *reinterpret_cast<const f32x4*>(&b1[e * H_ + hb]);
            u16 o[4];
            #pragma unroll
            for (int r = 0; r < 4; ++r) {
                float h = acc[m][n][r] + bias[r];
                float g = 0.5f * h * (1.0f + erff(h * 0.70710678118f));
                o[r] = f2bf_n(g);
            }
            const int lc = (n * 2 + (lk >> 1)) ^ (row & 7);
            u16* p = Himg + hblk + row * 64 + lc * 8 + (lk & 1) * 4;
            *reinterpret_cast<u64*>(p) = *reinterpret_cast<const u64*>(o);
        }
    }
}

// ---------------- GEMM2 v7: persistent B-panel in LDS, 1 block/CU ----------
// grid (x=32 be -> XCD=e, y=8 nt), 512 thr (8 waves 2Mx4N, wave 32x64).
// LDS = Bs 128KB (full W2 panel, loaded once) + As 32KB = 160KB exactly.
// Per block: 16 m-tiles of 64 rows; A staged per-mt from L2-local Himg.
__global__ __launch_bounds__(512) void gemm2_v7(
    const u16* __restrict__ Himg, const u16* __restrict__ W2img,
    const float* __restrict__ b2, const float* __restrict__ gate,
    u16* __restrict__ Ybuf)
{
    const int be = blockIdx.x;          // XCD = be%8 = e
    const int nt = blockIdx.y;          // 0..7
    const int b = be >> 3, e = be & 7;
    const int n0 = nt * 256;

    __shared__ __align__(16) u16 As[16384];   // 32 KB: [kt4][row64][sc8]
    __shared__ __align__(16) u16 Bs[65536];   // 128 KB: [kt4][row256][sc8]

    const int tid = threadIdx.x;
    const int lane = tid & 63, wid = tid >> 6;
    const int wm = wid >> 2, wn = wid & 3;
    const int l15 = lane & 15, lk = lane >> 4;
    const int wofs = wid * 512;

    // B panel: load once (16 x 16B DMA per thread)
    const u16* bPanel = W2img + (size_t)(e * 8 + nt) * 65536;
    #pragma unroll
    for (int j = 0; j < 16; ++j)
        gload16(bPanel + (size_t)(j * 512 + tid) * 8, &Bs[j * 4096 + wofs]);

    const u16* aBase = Himg + (size_t)(be * 16) * 16384 + (size_t)tid * 8;

#define A_ISSUE(mt)                                                           \
    do {                                                                      \
        const u16* a_ = aBase + (size_t)(mt) * 16384;                         \
        gload16(a_,          &As[wofs]);                                      \
        gload16(a_ + 4096,   &As[4096 + wofs]);                               \
        gload16(a_ + 8192,   &As[8192 + wofs]);                               \
        gload16(a_ + 12288,  &As[12288 + wofs]);                              \
    } while (0)

    A_ISSUE(0);

    // hoisted bias (static-indexed registers)
    f32x4 bias[4];
    #pragma unroll
    for (int n = 0; n < 4; ++n)
        bias[n] = *reinterpret_cast<const f32x4*>(
            &b2[n0 + wn * 64 + n * 16 + lk * 4]);

    const int gbase = (b * E_ + e) * C_;
    const size_t ybase = (size_t)(b * E_ + e) * C_;

    asm volatile("s_waitcnt vmcnt(0)" ::: "memory");   // B + A(0) landed
    __builtin_amdgcn_s_barrier();
    __builtin_amdgcn_sched_barrier(0);

    for (int mt = 0; mt < 16; ++mt) {
        f32x4 acc[2][4];
        #pragma unroll
        for (int i = 0; i < 2; ++i)
            #pragma unroll
            for (int j = 0; j < 4; ++j)
                acc[i][j] = (f32x4){0.f, 0.f, 0.f, 0.f};

        #pragma unroll
        for (int t = 0; t < 4; ++t) {
            #pragma unroll
            for (int kk = 0; kk < 2; ++kk) {
                short8 af[2], bfr[4];
                #pragma unroll
                for (int m = 0; m < 2; ++m) {
                    const int row = wm * 32 + m * 16 + l15;
                    af[m] = *reinterpret_cast<const short8*>(
                        &As[t * 4096 + swz(row, kk * 4 + lk)]);
                }
                #pragma unroll
                for (int n = 0; n < 4; ++n) {
                    const int row = wn * 64 + n * 16 + l15;
                    bfr[n] = *reinterpret_cast<const short8*>(
                        &Bs[t * 16384 + swz(row, kk * 4 + lk)]);
                }
                __builtin_amdgcn_s_setprio(1);
                #pragma unroll
                for (int m = 0; m < 2; ++m)
                    #pragma unroll
                    for (int n = 0; n < 4; ++n)
                        acc[m][n] = __builtin_amdgcn_mfma_f32_16x16x32_bf16(
                            bfr[n], af[m], acc[m][n], 0, 0, 0);
                __builtin_amdgcn_s_setprio(0);
            }
        }

        // all waves done reading As -> safe to overwrite
        asm volatile("s_waitcnt lgkmcnt(0)" ::: "memory");
        __builtin_amdgcn_s_barrier();
        __builtin_amdgcn_sched_barrier(0);

        // gate loads FIRST (so their dependence wait doesn't drain A loads)
        const float g0 = gate[gbase + mt * 64 + wm * 32 + l15];
        const float g1 = gate[gbase + mt * 64 + wm * 32 + 16 + l15];
        if (mt < 15) A_ISSUE(mt + 1);

        // epilogue: (acc + b2) * gate -> Ybuf rows (8x 8B stores)
        #pragma unroll
        for (int m = 0; m < 2; ++m) {
            const int cl = wm * 32 + m * 16 + l15;
            const float g = (m == 0) ? g0 : g1;
            u16* rowp = Ybuf + (ybase + mt * 64 + cl) * (size_t)D_ + n0;
            #pragma unroll
            for (int n = 0; n < 4; ++n) {
                const int db = wn * 64 + n * 16 + lk * 4;
                u16 o[4];
                #pragma unroll
                for (int r = 0; r < 4; ++r)
                    o[r] = f2bf_n((acc[m][n][r] + bias[n][r]) * g);
                *reinterpret_cast<u64*>(rowp + db) =
                    *reinterpret_cast<const u64*>(o);
            }
        }

        if (mt < 15) {
            // 4 A-loads are oldest among <= {4 loads + 8 stores}: vmcnt(8)
            // releases A without draining epilogue stores.
            asm volatile("s_waitcnt vmcnt(8)" ::: "memory");
            __builtin_amdgcn_s_barrier();
            __builtin_amdgcn_sched_barrier(0);
        }
    }
#undef A_ISSUE
}

// ---------------- inverted index build ----------------
__global__ __launch_bounds__(256) void fill_kernel(
    const int* __restrict__ idx, int* __restrict__ cnt,
    int* __restrict__ slots)
{
    int i = blockIdx.x * 256 + threadIdx.x;
    if (i >= B_ * E_ * C_) return;
    int b = i / (E_ * C_);
    int slot = i % (E_ * C_);
    int t = idx[i];
    int p = atomicAdd(&cnt[b * T_ + t], 1);
    if (p < SLOTCAP) slots[(b * T_ + t) * SLOTCAP + p] = slot;
}

// ---------------- combine: out[b,t,:] = sum over slots of Ybuf ----------------
__global__ __launch_bounds__(256) void combine_kernel(
    const u16* __restrict__ Ybuf, const int* __restrict__ cnt,
    const int* __restrict__ slots, float* __restrict__ out)
{
    const int bt = blockIdx.x;               // b*T_ + t
    const int tid = threadIdx.x;
    __shared__ int sl[SLOTCAP];
    int n = cnt[bt];
    n = n > SLOTCAP ? SLOTCAP : n;
    if (tid < n) sl[tid] = slots[bt * SLOTCAP + tid];
    __syncthreads();
    const int b = bt >> 12;                  // T_ = 4096
    float a[8] = {0.f, 0.f, 0.f, 0.f, 0.f, 0.f, 0.f, 0.f};
    for (int s = 0; s < n; ++s) {
        const u16* yrow = Ybuf + ((size_t)b * (E_ * C_) + sl[s]) * D_ + tid * 8;
        short8 v = *reinterpret_cast<const short8*>(yrow);
        #pragma unroll
        for (int j = 0; j < 8; ++j) a[j] += bf2f((u16)v[j]);
    }
    float* orow = out + (size_t)bt * D_ + tid * 8;
    *reinterpret_cast<f32x4*>(orow)     = (f32x4){a[0], a[1], a[2], a[3]};
    *reinterpret_cast<f32x4*>(orow + 4) = (f32x4){a[4], a[5], a[6], a[7]};
}

extern "C" void kernel_launch(void* const* d_in, const int* in_sizes, int n_in,
                              void* d_out, int out_size, void* d_ws, size_t ws_size,
                              hipStream_t stream) {
    const float* x    = (const float*)d_in[0];
    const float* W1   = (const float*)d_in[1];
    const float* b1   = (const float*)d_in[2];
    const float* W2   = (const float*)d_in[3];
    const float* b2   = (const float*)d_in[4];
    const int*   idx  = (const int*)d_in[5];
    const float* gate = (const float*)d_in[6];
    float* out = (float*)d_out;

    const size_t nW = (size_t)E_ * H_ * D_;        // 4,194,304
    const size_t nX = (size_t)B_ * T_ * D_;        // 33,554,432
    const size_t nH = (size_t)B_ * E_ * C_ * H_;   // 8,388,608
    const size_t nY = (size_t)B_ * E_ * C_ * D_;   // 67,108,864

    // ws layout: [W1img][W2img][Himg][Ybuf (aliased as xbf)][cnt][slots]
    u16* W1img = (u16*)d_ws;
    u16* W2img = W1img + nW;
    u16* Himg  = W2img + nW;
    u16* Ybuf  = Himg + nH;
    u16* xbf   = Ybuf;                 // alias: xbf dead before gemm2 writes Ybuf
    int* cnt   = (int*)(Ybuf + nY);
    int* slots = cnt + (size_t)B_ * T_;

    hipMemsetAsync(cnt, 0, (size_t)B_ * T_ * sizeof(int), stream);
    conv_w1_img<<<2048, 256, 0, stream>>>(W1, W1img);
    conv_w2_img<<<2048, 256, 0, stream>>>(W2, W2img);
    conv_x_bf16<<<(int)(nX / 1024), 256, 0, stream>>>(x, xbf, (int)nX);
    fill_kernel<<<(B_ * E_ * C_) / 256, 256, 0, stream>>>(idx, cnt, slots);

    gemm1_v8<<<dim3(32, 16), 512, 0, stream>>>(xbf, W1img, b1, idx, Himg);
    gemm2_v7<<<dim3(32, 8), 512, 0, stream>>>(Himg, W2img, b2, gate, Ybuf);
    combine_kernel<<<B_ * T_, 256, 0, stream>>>(Ybuf, cnt, slots, out);
}

// Round 12
// 215.498 us; speedup vs baseline: 1.2127x; 1.0129x over previous
//
#include <hip/hip_runtime.h>
#include <hip/hip_bf16.h>
#include <math.h>

#define B_ 4
#define T_ 4096
#define D_ 2048
#define E_ 8
#define C_ 1024
#define H_ 256
#define SLOTCAP 32

typedef unsigned short u16;
typedef unsigned long long u64;
typedef __attribute__((ext_vector_type(8))) short short8;
typedef __attribute__((ext_vector_type(4))) float f32x4;

__device__ __forceinline__ u16 f2bf_n(float f) {
    union { __hip_bfloat16 b; u16 u; } v;
    v.b = __float2bfloat16(f);
    return v.u;
}
__device__ __forceinline__ float bf2f(u16 u) {
    union { unsigned u; float f; } v; v.u = ((unsigned)u) << 16;
    return v.f;
}

// swizzled u16 index into a [rows][64] tile image: 8-u16 chunk XOR'd by row&7
__device__ __forceinline__ int swz(int row, int chunk) {
    return (row << 6) + ((chunk ^ (row & 7)) << 3);
}

// async global->LDS, 16B per lane; dst wave-uniform base (HW adds lane*16)
__device__ __forceinline__ void gload16(const void* g, void* l) {
    __builtin_amdgcn_global_load_lds(
        (const __attribute__((address_space(1))) void*)g,
        (__attribute__((address_space(3))) void*)l, 16, 0, 0);
}

// ---------------- W1 -> swizzled tile image ----------------
// image[e][kt(32)][row(256)][sc(8)] : chunk = bf16(W1[e][row][kt*64 + (sc^(row&7))*8..])
__global__ __launch_bounds__(256) void conv_w1_img(
    const float* __restrict__ W1, u16* __restrict__ img)
{
    const int cid = blockIdx.x * 256 + threadIdx.x;
    const int e = cid >> 16;
    const int kt = (cid >> 11) & 31;
    const int row = (cid >> 3) & 255;
    const int sc = cid & 7;
    const float* s = W1 + (((size_t)e * 256 + row) * 2048 + kt * 64
                           + ((sc ^ (row & 7)) << 3));
    f32x4 v0 = *reinterpret_cast<const f32x4*>(s);
    f32x4 v1 = *reinterpret_cast<const f32x4*>(s + 4);
    u16 o[8];
    #pragma unroll
    for (int j = 0; j < 4; ++j) { o[j] = f2bf_n(v0[j]); o[j + 4] = f2bf_n(v1[j]); }
    *reinterpret_cast<short8*>(img + (size_t)cid * 8) =
        *reinterpret_cast<const short8*>(o);
}

// ---------------- W2 -> swizzled tile image ----------------
// image[e][nt(8)][kt(4)][row(256)][sc(8)]
__global__ __launch_bounds__(256) void conv_w2_img(
    const float* __restrict__ W2, u16* __restrict__ img)
{
    const int cid = blockIdx.x * 256 + threadIdx.x;
    const int e = cid >> 16;
    const int nt = (cid >> 13) & 7;
    const int kt = (cid >> 11) & 3;
    const int row = (cid >> 3) & 255;
    const int sc = cid & 7;
    const float* s = W2 + (((size_t)e * 2048 + nt * 256 + row) * 256 + kt * 64
                           + ((sc ^ (row & 7)) << 3));
    f32x4 v0 = *reinterpret_cast<const f32x4*>(s);
    f32x4 v1 = *reinterpret_cast<const f32x4*>(s + 4);
    u16 o[8];
    #pragma unroll
    for (int j = 0; j < 4; ++j) { o[j] = f2bf_n(v0[j]); o[j + 4] = f2bf_n(v1[j]); }
    *reinterpret_cast<short8*>(img + (size_t)cid * 8) =
        *reinterpret_cast<const short8*>(o);
}

// ---------------- zero cnt (replaces hipMemsetAsync) ----------------
__global__ __launch_bounds__(256) void zero_cnt(int* __restrict__ cnt)
{
    const int i = (blockIdx.x * 256 + threadIdx.x) * 4;
    *reinterpret_cast<f32x4*>(cnt + i) = (f32x4){0.f, 0.f, 0.f, 0.f};
}

// ---------------- GEMM1 v9: fused f32-gather + cvt (A reg-staged),
// B via gload_lds depth-2, 64x256 tile, 2 blocks/CU --------------------------
// grid (x=32 be -> XCD=e, y=16 mt), 512 thr (8 waves 2Mx4N, wave 32x64)
__global__ __launch_bounds__(512) void gemm1_v9(
    const float* __restrict__ x, const u16* __restrict__ W1img,
    const float* __restrict__ b1, const int* __restrict__ idx,
    u16* __restrict__ Himg)
{
    const int be = blockIdx.x;          // XCD = be%8 = e
    const int mt = blockIdx.y;          // 0..15
    const int b = be >> 3, e = be & 7;
    const int m0 = mt * 64;

    __shared__ __align__(16) u16 As[2][4096];    // 8 KB each
    __shared__ __align__(16) u16 Bs[2][16384];   // 32 KB each

    const int tid = threadIdx.x;
    const int lane = tid & 63, wid = tid >> 6;
    const int wm = wid >> 2, wn = wid & 3;
    const int l15 = lane & 15, lk = lane >> 4;

    // A: thread covers (row = tid>>3, chunk sc = tid&7) of the 64x64 tile.
    // f32 source, linear chunk; ds_write at swizzled offset.
    const int row8 = tid >> 3, asc = tid & 7;
    const int tok = idx[(b * E_ + e) * C_ + m0 + row8];
    const float* aRow = x + ((size_t)b * T_ + tok) * D_ + asc * 8;
    const int aOff = swz(row8, asc);

    const u16* bSrc = W1img + (size_t)e * 32 * 16384 + (size_t)tid * 8;
    const int wofs = wid * 512;   // wave-uniform LDS base (u16)

#define B_ISSUE(buf, t)                                                       \
    do {                                                                      \
        const u16* b_ = bSrc + (size_t)(t) * 16384;                           \
        gload16(b_,         &Bs[buf][wofs]);                                  \
        gload16(b_ + 4096,  &Bs[buf][4096 + wofs]);                           \
        gload16(b_ + 8192,  &Bs[buf][8192 + wofs]);                           \
        gload16(b_ + 12288, &Bs[buf][12288 + wofs]);                          \
    } while (0)

#define A_STAGE(buf, t)                                                       \
    do {                                                                      \
        f32x4 v0 = *reinterpret_cast<const f32x4*>(aRow + (t) * 64);          \
        f32x4 v1 = *reinterpret_cast<const f32x4*>(aRow + (t) * 64 + 4);      \
        short8 s;                                                             \
        _Pragma("unroll")                                                     \
        for (int r = 0; r < 4; ++r) {                                         \
            s[r] = (short)f2bf_n(v0[r]); s[r + 4] = (short)f2bf_n(v1[r]);     \
        }                                                                     \
        *reinterpret_cast<short8*>(&As[buf][aOff]) = s;                       \
    } while (0)

    f32x4 acc[2][4];
    #pragma unroll
    for (int i = 0; i < 2; ++i)
        #pragma unroll
        for (int j = 0; j < 4; ++j)
            acc[i][j] = (f32x4){0.f, 0.f, 0.f, 0.f};

    // prologue: stage tiles 0,1 (A reg->LDS, B async DMA)
    B_ISSUE(0, 0);
    B_ISSUE(1, 1);
    A_STAGE(0, 0);
    A_STAGE(1, 1);
    asm volatile("s_waitcnt lgkmcnt(0)" ::: "memory");  // own A ds_writes done

    const int NT = D_ / 64;  // 32
    for (int t = 0; t < NT; ++t) {
        const int cur = t & 1;
        // head: B(t) landed (newest 4 = B(t+1) may remain in flight)
        if (t < NT - 1) asm volatile("s_waitcnt vmcnt(4)" ::: "memory");
        else            asm volatile("s_waitcnt vmcnt(0)" ::: "memory");
        __builtin_amdgcn_s_barrier();
        __builtin_amdgcn_sched_barrier(0);
        #pragma unroll
        for (int kk = 0; kk < 2; ++kk) {
            short8 af[2], bfr[4];
            #pragma unroll
            for (int m = 0; m < 2; ++m) {
                const int row = wm * 32 + m * 16 + l15;
                af[m] = *reinterpret_cast<const short8*>(
                    &As[cur][swz(row, kk * 4 + lk)]);
            }
            #pragma unroll
            for (int n = 0; n < 4; ++n) {
                const int row = wn * 64 + n * 16 + l15;
                bfr[n] = *reinterpret_cast<const short8*>(
                    &Bs[cur][swz(row, kk * 4 + lk)]);
            }
            __builtin_amdgcn_s_setprio(1);
            #pragma unroll
            for (int m = 0; m < 2; ++m)
                #pragma unroll
                for (int n = 0; n < 4; ++n)
                    acc[m][n] = __builtin_amdgcn_mfma_f32_16x16x32_bf16(
                        bfr[n], af[m], acc[m][n], 0, 0, 0);
            __builtin_amdgcn_s_setprio(0);
        }
        // own ds_reads (and any prior ds_writes) drained; then free-buffer barrier
        asm volatile("s_waitcnt lgkmcnt(0)" ::: "memory");
        __builtin_amdgcn_s_barrier();
        __builtin_amdgcn_sched_barrier(0);
        if (t + 2 < NT) {
            B_ISSUE(cur, t + 2);      // async, stays in flight across barriers
            A_STAGE(cur, t + 2);      // f32 loads -> cvt -> ds_write (lgkm-covered
                                      // by next iter's lgkmcnt(0) before barrier)
        }
    }
#undef B_ISSUE
#undef A_STAGE

    // epilogue: bias + exact gelu -> Himg (64-row tile images)
    const size_t hblk = ((size_t)(be * 16 + mt) * 4 + wn) * 4096;
    #pragma unroll
    for (int m = 0; m < 2; ++m) {
        const int row = wm * 32 + m * 16 + l15;
        #pragma unroll
        for (int n = 0; n < 4; ++n) {
            const int hb = wn * 64 + n * 16 + lk * 4;
            f32x4 bias = *reinterpret_cast<const f32x4*>(&b1[e * H_ + hb]);
            u16 o[4];
            #pragma unroll
            for (int r = 0; r < 4; ++r) {
                float h = acc[m][n][r] + bias[r];
                float g = 0.5f * h * (1.0f + erff(h * 0.70710678118f));
                o[r] = f2bf_n(g);
            }
            const int lc = (n * 2 + (lk >> 1)) ^ (row & 7);
            u16* p = Himg + hblk + row * 64 + lc * 8 + (lk & 1) * 4;
            *reinterpret_cast<u64*>(p) = *reinterpret_cast<const u64*>(o);
        }
    }
}

// ---------------- GEMM2 v7: persistent B-panel in LDS, 1 block/CU ----------
__global__ __launch_bounds__(512) void gemm2_v7(
    const u16* __restrict__ Himg, const u16* __restrict__ W2img,
    const float* __restrict__ b2, const float* __restrict__ gate,
    u16* __restrict__ Ybuf)
{
    const int be = blockIdx.x;          // XCD = be%8 = e
    const int nt = blockIdx.y;          // 0..7
    const int b = be >> 3, e = be & 7;
    const int n0 = nt * 256;

    __shared__ __align__(16) u16 As[16384];   // 32 KB: [kt4][row64][sc8]
    __shared__ __align__(16) u16 Bs[65536];   // 128 KB: [kt4][row256][sc8]

    const int tid = threadIdx.x;
    const int lane = tid & 63, wid = tid >> 6;
    const int wm = wid >> 2, wn = wid & 3;
    const int l15 = lane & 15, lk = lane >> 4;
    const int wofs = wid * 512;

    const u16* bPanel = W2img + (size_t)(e * 8 + nt) * 65536;
    #pragma unroll
    for (int j = 0; j < 16; ++j)
        gload16(bPanel + (size_t)(j * 512 + tid) * 8, &Bs[j * 4096 + wofs]);

    const u16* aBase = Himg + (size_t)(be * 16) * 16384 + (size_t)tid * 8;

#define A_ISSUE(mt)                                                           \
    do {                                                                      \
        const u16* a_ = aBase + (size_t)(mt) * 16384;                         \
        gload16(a_,          &As[wofs]);                                      \
        gload16(a_ + 4096,   &As[4096 + wofs]);                               \
        gload16(a_ + 8192,   &As[8192 + wofs]);                               \
        gload16(a_ + 12288,  &As[12288 + wofs]);                              \
    } while (0)

    A_ISSUE(0);

    f32x4 bias[4];
    #pragma unroll
    for (int n = 0; n < 4; ++n)
        bias[n] = *reinterpret_cast<const f32x4*>(
            &b2[n0 + wn * 64 + n * 16 + lk * 4]);

    const int gbase = (b * E_ + e) * C_;
    const size_t ybase = (size_t)(b * E_ + e) * C_;

    asm volatile("s_waitcnt vmcnt(0)" ::: "memory");
    __builtin_amdgcn_s_barrier();
    __builtin_amdgcn_sched_barrier(0);

    for (int mt = 0; mt < 16; ++mt) {
        f32x4 acc[2][4];
        #pragma unroll
        for (int i = 0; i < 2; ++i)
            #pragma unroll
            for (int j = 0; j < 4; ++j)
                acc[i][j] = (f32x4){0.f, 0.f, 0.f, 0.f};

        #pragma unroll
        for (int t = 0; t < 4; ++t) {
            #pragma unroll
            for (int kk = 0; kk < 2; ++kk) {
                short8 af[2], bfr[4];
                #pragma unroll
                for (int m = 0; m < 2; ++m) {
                    const int row = wm * 32 + m * 16 + l15;
                    af[m] = *reinterpret_cast<const short8*>(
                        &As[t * 4096 + swz(row, kk * 4 + lk)]);
                }
                #pragma unroll
                for (int n = 0; n < 4; ++n) {
                    const int row = wn * 64 + n * 16 + l15;
                    bfr[n] = *reinterpret_cast<const short8*>(
                        &Bs[t * 16384 + swz(row, kk * 4 + lk)]);
                }
                __builtin_amdgcn_s_setprio(1);
                #pragma unroll
                for (int m = 0; m < 2; ++m)
                    #pragma unroll
                    for (int n = 0; n < 4; ++n)
                        acc[m][n] = __builtin_amdgcn_mfma_f32_16x16x32_bf16(
                            bfr[n], af[m], acc[m][n], 0, 0, 0);
                __builtin_amdgcn_s_setprio(0);
            }
        }

        asm volatile("s_waitcnt lgkmcnt(0)" ::: "memory");
        __builtin_amdgcn_s_barrier();
        __builtin_amdgcn_sched_barrier(0);

        const float g0 = gate[gbase + mt * 64 + wm * 32 + l15];
        const float g1 = gate[gbase + mt * 64 + wm * 32 + 16 + l15];
        if (mt < 15) A_ISSUE(mt + 1);

        #pragma unroll
        for (int m = 0; m < 2; ++m) {
            const int cl = wm * 32 + m * 16 + l15;
            const float g = (m == 0) ? g0 : g1;
            u16* rowp = Ybuf + (ybase + mt * 64 + cl) * (size_t)D_ + n0;
            #pragma unroll
            for (int n = 0; n < 4; ++n) {
                const int db = wn * 64 + n * 16 + lk * 4;
                u16 o[4];
                #pragma unroll
                for (int r = 0; r < 4; ++r)
                    o[r] = f2bf_n((acc[m][n][r] + bias[n][r]) * g);
                *reinterpret_cast<u64*>(rowp + db) =
                    *reinterpret_cast<const u64*>(o);
            }
        }

        if (mt < 15) {
            asm volatile("s_waitcnt vmcnt(8)" ::: "memory");
            __builtin_amdgcn_s_barrier();
            __builtin_amdgcn_sched_barrier(0);
        }
    }
#undef A_ISSUE
}

// ---------------- inverted index build ----------------
__global__ __launch_bounds__(256) void fill_kernel(
    const int* __restrict__ idx, int* __restrict__ cnt,
    int* __restrict__ slots)
{
    int i = blockIdx.x * 256 + threadIdx.x;
    if (i >= B_ * E_ * C_) return;
    int b = i / (E_ * C_);
    int slot = i % (E_ * C_);
    int t = idx[i];
    int p = atomicAdd(&cnt[b * T_ + t], 1);
    if (p < SLOTCAP) slots[(b * T_ + t) * SLOTCAP + p] = slot;
}

// ---------------- combine: out[b,t,:] = sum over slots of Ybuf ----------------
__global__ __launch_bounds__(256) void combine_kernel(
    const u16* __restrict__ Ybuf, const int* __restrict__ cnt,
    const int* __restrict__ slots, float* __restrict__ out)
{
    const int bt = blockIdx.x;               // b*T_ + t
    const int tid = threadIdx.x;
    __shared__ int sl[SLOTCAP];
    int n = cnt[bt];
    n = n > SLOTCAP ? SLOTCAP : n;
    if (tid < n) sl[tid] = slots[bt * SLOTCAP + tid];
    __syncthreads();
    const int b = bt >> 12;                  // T_ = 4096
    float a[8] = {0.f, 0.f, 0.f, 0.f, 0.f, 0.f, 0.f, 0.f};
    for (int s = 0; s < n; ++s) {
        const u16* yrow = Ybuf + ((size_t)b * (E_ * C_) + sl[s]) * D_ + tid * 8;
        short8 v = *reinterpret_cast<const short8*>(yrow);
        #pragma unroll
        for (int j = 0; j < 8; ++j) a[j] += bf2f((u16)v[j]);
    }
    float* orow = out + (size_t)bt * D_ + tid * 8;
    *reinterpret_cast<f32x4*>(orow)     = (f32x4){a[0], a[1], a[2], a[3]};
    *reinterpret_cast<f32x4*>(orow + 4) = (f32x4){a[4], a[5], a[6], a[7]};
}

extern "C" void kernel_launch(void* const* d_in, const int* in_sizes, int n_in,
                              void* d_out, int out_size, void* d_ws, size_t ws_size,
                              hipStream_t stream) {
    const float* x    = (const float*)d_in[0];
    const float* W1   = (const float*)d_in[1];
    const float* b1   = (const float*)d_in[2];
    const float* W2   = (const float*)d_in[3];
    const float* b2   = (const float*)d_in[4];
    const int*   idx  = (const int*)d_in[5];
    const float* gate = (const float*)d_in[6];
    float* out = (float*)d_out;

    const size_t nW = (size_t)E_ * H_ * D_;        // 4,194,304
    const size_t nH = (size_t)B_ * E_ * C_ * H_;   // 8,388,608
    const size_t nY = (size_t)B_ * E_ * C_ * D_;   // 67,108,864

    // ws layout: [W1img][W2img][Himg][Ybuf][cnt][slots]
    u16* W1img = (u16*)d_ws;
    u16* W2img = W1img + nW;
    u16* Himg  = W2img + nW;
    u16* Ybuf  = Himg + nH;
    int* cnt   = (int*)(Ybuf + nY);
    int* slots = cnt + (size_t)B_ * T_;

    zero_cnt<<<(B_ * T_) / 1024, 256, 0, stream>>>(cnt);
    conv_w1_img<<<2048, 256, 0, stream>>>(W1, W1img);
    conv_w2_img<<<2048, 256, 0, stream>>>(W2, W2img);
    fill_kernel<<<(B_ * E_ * C_) / 256, 256, 0, stream>>>(idx, cnt, slots);

    gemm1_v9<<<dim3(32, 16), 512, 0, stream>>>(x, W1img, b1, idx, Himg);
    gemm2_v7<<<dim3(32, 8), 512, 0, stream>>>(Himg, W2img, b2, gate, Ybuf);
    combine_kernel<<<B_ * T_, 256, 0, stream>>>(Ybuf, cnt, slots, out);
}